// Round 1
// baseline (43.965 us; speedup 1.0000x reference)
//
#include <hip/hip_runtime.h>
#include <hip/hip_bf16.h>

#define HD   512
#define SQ   2048
#define BQ   4
#define MTOT (BQ*SQ)   /* 8192 rows */
#define EPS  1e-5f

typedef short bf16x8 __attribute__((ext_vector_type(8)));
typedef float f32x4  __attribute__((ext_vector_type(4)));

__device__ __forceinline__ float bf2f(unsigned short u) {
    union { unsigned int u32; float f; } c; c.u32 = ((unsigned int)u) << 16; return c.f;
}
__device__ __forceinline__ unsigned short f2bf(float f) {
    __hip_bfloat16 h = __float2bfloat16(f);   // RNE
    return __builtin_bit_cast(unsigned short, h);
}

// ---------------------------------------------------------------------------
// K0: fp = static @ Wf^T + bf   (blocks 0..511, one wave per (b,k) pair)
//     Wob = bf16(Wo)            (blocks 512..639)
// ---------------------------------------------------------------------------
__global__ void k0_fp_conv(const float* __restrict__ sf, const float* __restrict__ Wf,
                           const float* __restrict__ bfv, const float* __restrict__ Wo,
                           float* __restrict__ fp, unsigned short* __restrict__ Wob) {
    int t = threadIdx.x;
    int blk = blockIdx.x;
    if (blk < 512) {
        int pair = blk * 4 + (t >> 6);          // 0..2047
        int b = pair >> 9;                      // /512
        int k = pair & 511;
        int lane = t & 63;
        const float4* s4 = (const float4*)(sf + b * HD + lane * 8);
        const float4* w4 = (const float4*)(Wf + (size_t)k * HD + lane * 8);
        float4 sa = s4[0], sb = s4[1], wa = w4[0], wb = w4[1];
        float p = sa.x*wa.x + sa.y*wa.y + sa.z*wa.z + sa.w*wa.w
                + sb.x*wb.x + sb.y*wb.y + sb.z*wb.z + sb.w*wb.w;
        #pragma unroll
        for (int off = 32; off; off >>= 1) p += __shfl_xor(p, off);
        if (lane == 0) fp[b * HD + k] = p + bfv[k];
    } else {
        int base = (blk - 512) * 2048 + t * 8;  // covers 512*512 = 262144 elems
        float4 a = *(const float4*)(Wo + base);
        float4 c = *(const float4*)(Wo + base + 4);
        union { unsigned short us[8]; uint4 v4; } pk;
        pk.us[0]=f2bf(a.x); pk.us[1]=f2bf(a.y); pk.us[2]=f2bf(a.z); pk.us[3]=f2bf(a.w);
        pk.us[4]=f2bf(c.x); pk.us[5]=f2bf(c.y); pk.us[6]=f2bf(c.z); pk.us[7]=f2bf(c.w);
        *(uint4*)(Wob + base) = pk.v4;
    }
}

// ---------------------------------------------------------------------------
// K1: out1 = LN(temporal + fp[b])  -> bf16.  One wave per row.
// ---------------------------------------------------------------------------
__global__ void k1_ln1(const float* __restrict__ x, const float* __restrict__ fp,
                       const float* __restrict__ g1, const float* __restrict__ b1,
                       unsigned short* __restrict__ out1b) {
    int r = blockIdx.x * 4 + (threadIdx.x >> 6);
    int lane = threadIdx.x & 63;
    int b = r >> 11;                            // 2048 rows per batch
    const float4* xr = (const float4*)(x + (size_t)r * HD + lane * 8);
    const float4* fr = (const float4*)(fp + b * HD + lane * 8);
    float v[8];
    {
        float4 x0 = xr[0], x1 = xr[1], f0 = fr[0], f1 = fr[1];
        v[0]=x0.x+f0.x; v[1]=x0.y+f0.y; v[2]=x0.z+f0.z; v[3]=x0.w+f0.w;
        v[4]=x1.x+f1.x; v[5]=x1.y+f1.y; v[6]=x1.z+f1.z; v[7]=x1.w+f1.w;
    }
    float s = 0.f, q = 0.f;
    #pragma unroll
    for (int j = 0; j < 8; ++j) { s += v[j]; q += v[j] * v[j]; }
    #pragma unroll
    for (int off = 32; off; off >>= 1) { s += __shfl_xor(s, off); q += __shfl_xor(q, off); }
    float mean = s * (1.f / HD);
    float var  = q * (1.f / HD) - mean * mean;
    float rs   = rsqrtf(var + EPS);
    float g[8], bb[8];
    {
        const float4* g4 = (const float4*)(g1 + lane * 8);
        const float4* b4 = (const float4*)(b1 + lane * 8);
        float4 ga = g4[0], gb = g4[1], ba = b4[0], bbv = b4[1];
        g[0]=ga.x; g[1]=ga.y; g[2]=ga.z; g[3]=ga.w; g[4]=gb.x; g[5]=gb.y; g[6]=gb.z; g[7]=gb.w;
        bb[0]=ba.x; bb[1]=ba.y; bb[2]=ba.z; bb[3]=ba.w; bb[4]=bbv.x; bb[5]=bbv.y; bb[6]=bbv.z; bb[7]=bbv.w;
    }
    union { unsigned short us[8]; uint4 v4; } pk;
    #pragma unroll
    for (int j = 0; j < 8; ++j) pk.us[j] = f2bf((v[j] - mean) * rs * g[j] + bb[j]);
    *(uint4*)(out1b + (size_t)r * HD + lane * 8) = pk.v4;
}

// ---------------------------------------------------------------------------
// K2: proj = out1 @ Wo^T + bo   (M=8192, N=512, K=512, bf16 MFMA, f32 out)
//     Block: 32 rows x 512 cols, 4 waves (each wave owns a 128-col strip).
//     LDS rows padded 32->40 bf16 (80 B) to break the 8-way bank conflict.
// ---------------------------------------------------------------------------
__global__ __launch_bounds__(256) void k2_gemm(
        const unsigned short* __restrict__ A,   // out1 bf16 [8192][512]
        const unsigned short* __restrict__ Bw,  // Wo bf16   [512][512]  (B^T layout: [n][k])
        const float* __restrict__ bo,
        float* __restrict__ proj) {
    __shared__ unsigned short As[32 * 40];
    __shared__ unsigned short Bs[512 * 40];
    int t = threadIdx.x;
    int m0 = blockIdx.x * 32;
    int lane = t & 63, w = t >> 6;
    int rl = lane & 15, kl = lane >> 4;

    f32x4 acc[2][8];
    #pragma unroll
    for (int i = 0; i < 2; ++i)
        #pragma unroll
        for (int j = 0; j < 8; ++j)
            acc[i][j] = (f32x4){0.f, 0.f, 0.f, 0.f};

    for (int k0 = 0; k0 < HD; k0 += 32) {
        if (t < 128) {  // A tile: 32 rows x 32 k  (4 x 16B chunks per row)
            int m = t >> 2, c = t & 3;
            *(uint4*)(&As[m * 40 + c * 8]) =
                *(const uint4*)(A + (size_t)(m0 + m) * HD + k0 + c * 8);
        }
        #pragma unroll
        for (int p = 0; p < 8; ++p) {  // B tile: 512 rows x 32 k
            int idx = p * 256 + t;
            int n = idx >> 2, c = idx & 3;
            *(uint4*)(&Bs[n * 40 + c * 8]) =
                *(const uint4*)(Bw + (size_t)n * HD + k0 + c * 8);
        }
        __syncthreads();
        // A frag: row = rl (+16), k = kl*8 + j   |   B frag: col-row n, same k
        bf16x8 a0 = *(const bf16x8*)(&As[rl * 40 + kl * 8]);
        bf16x8 a1 = *(const bf16x8*)(&As[(rl + 16) * 40 + kl * 8]);
        #pragma unroll
        for (int j = 0; j < 8; ++j) {
            bf16x8 bfr = *(const bf16x8*)(&Bs[(w * 128 + j * 16 + rl) * 40 + kl * 8]);
            acc[0][j] = __builtin_amdgcn_mfma_f32_16x16x32_bf16(a0, bfr, acc[0][j], 0, 0, 0);
            acc[1][j] = __builtin_amdgcn_mfma_f32_16x16x32_bf16(a1, bfr, acc[1][j], 0, 0, 0);
        }
        __syncthreads();
    }
    // C/D layout: col = lane&15, row = (lane>>4)*4 + reg   [m89-verified]
    #pragma unroll
    for (int i = 0; i < 2; ++i) {
        #pragma unroll
        for (int j = 0; j < 8; ++j) {
            int col = w * 128 + j * 16 + rl;
            int row = m0 + i * 16 + kl * 4;
            float boc = bo[col];
            #pragma unroll
            for (int r2 = 0; r2 < 4; ++r2)
                proj[(size_t)(row + r2) * HD + col] = acc[i][j][r2] + boc;
        }
    }
}

// ---------------------------------------------------------------------------
// K3: out = LN(out1 + proj)   (f32 out). One wave per row.
// ---------------------------------------------------------------------------
__global__ void k3_ln2(const unsigned short* __restrict__ o1, const float* __restrict__ proj,
                       const float* __restrict__ g2, const float* __restrict__ b2,
                       float* __restrict__ out) {
    int r = blockIdx.x * 4 + (threadIdx.x >> 6);
    int lane = threadIdx.x & 63;
    uint4 u = *(const uint4*)(o1 + (size_t)r * HD + lane * 8);
    const unsigned short* us = (const unsigned short*)&u;
    const float4* p4 = (const float4*)(proj + (size_t)r * HD + lane * 8);
    float v[8];
    {
        float4 p0 = p4[0], p1 = p4[1];
        v[0]=bf2f(us[0])+p0.x; v[1]=bf2f(us[1])+p0.y; v[2]=bf2f(us[2])+p0.z; v[3]=bf2f(us[3])+p0.w;
        v[4]=bf2f(us[4])+p1.x; v[5]=bf2f(us[5])+p1.y; v[6]=bf2f(us[6])+p1.z; v[7]=bf2f(us[7])+p1.w;
    }
    float s = 0.f, q = 0.f;
    #pragma unroll
    for (int j = 0; j < 8; ++j) { s += v[j]; q += v[j] * v[j]; }
    #pragma unroll
    for (int off = 32; off; off >>= 1) { s += __shfl_xor(s, off); q += __shfl_xor(q, off); }
    float mean = s * (1.f / HD);
    float var  = q * (1.f / HD) - mean * mean;
    float rs   = rsqrtf(var + EPS);
    float g[8], bb[8];
    {
        const float4* g4 = (const float4*)(g2 + lane * 8);
        const float4* b4 = (const float4*)(b2 + lane * 8);
        float4 ga = g4[0], gb = g4[1], ba = b4[0], bbv = b4[1];
        g[0]=ga.x; g[1]=ga.y; g[2]=ga.z; g[3]=ga.w; g[4]=gb.x; g[5]=gb.y; g[6]=gb.z; g[7]=gb.w;
        bb[0]=ba.x; bb[1]=ba.y; bb[2]=ba.z; bb[3]=ba.w; bb[4]=bbv.x; bb[5]=bbv.y; bb[6]=bbv.z; bb[7]=bbv.w;
    }
    float o[8];
    #pragma unroll
    for (int j = 0; j < 8; ++j) o[j] = (v[j] - mean) * rs * g[j] + bb[j];
    float4* o4 = (float4*)(out + (size_t)r * HD + lane * 8);
    o4[0] = make_float4(o[0], o[1], o[2], o[3]);
    o4[1] = make_float4(o[4], o[5], o[6], o[7]);
}

// ---------------------------------------------------------------------------
extern "C" void kernel_launch(void* const* d_in, const int* in_sizes, int n_in,
                              void* d_out, int out_size, void* d_ws, size_t ws_size,
                              hipStream_t stream) {
    const float* temporal = (const float*)d_in[0];
    const float* sf  = (const float*)d_in[1];
    // d_in[2] = Wt, d_in[3] = bt : provably unused (softmax over constant -> uniform)
    const float* Wf  = (const float*)d_in[4];
    const float* bfv = (const float*)d_in[5];
    const float* Wo  = (const float*)d_in[6];
    const float* bo  = (const float*)d_in[7];
    const float* g1  = (const float*)d_in[8];
    const float* b1  = (const float*)d_in[9];
    const float* g2  = (const float*)d_in[10];
    const float* b2  = (const float*)d_in[11];

    char* ws = (char*)d_ws;
    float*          fp    = (float*)ws;                               // 8 KB
    unsigned short* Wob   = (unsigned short*)(ws + 8192);             // 512 KB
    unsigned short* out1b = (unsigned short*)(ws + 8192 + 524288);    // 8 MB
    float*          proj  = (float*)(ws + 8192 + 524288 + 8388608);   // 16 MB

    k0_fp_conv<<<640,  256, 0, stream>>>(sf, Wf, bfv, Wo, fp, Wob);
    k1_ln1    <<<2048, 256, 0, stream>>>(temporal, fp, g1, b1, out1b);
    k2_gemm   <<<256,  256, 0, stream>>>(out1b, Wob, bo, proj);
    k3_ln2    <<<2048, 256, 0, stream>>>(out1b, proj, g2, b2, (float*)d_out);
}